// Round 15
// baseline (110.269 us; speedup 1.0000x reference)
//
#include <hip/hip_runtime.h>
#include <hip/hip_bf16.h>

#define NHEADS 12
#define HDIM   64
#define SEQ    1024
#define NBATCH 8
#define MODELD 768
#define QKVD   2304
#define BHEADS (NBATCH * NHEADS)   // 96
#define QKV_TILES 1152             // 64 m-tiles x 18 n-tiles
#define QKV_BLOCKS 512             // 2 per CU, persistent

typedef __attribute__((ext_vector_type(8))) short          bf16x8;
typedef __attribute__((ext_vector_type(8))) unsigned short u16x8;
typedef __attribute__((ext_vector_type(4))) unsigned short u16x4;
typedef __attribute__((ext_vector_type(4))) float          f32x4;

static __device__ __forceinline__ unsigned short f2bf(float f) {
  unsigned int u = __float_as_uint(f);
  u += 0x7fffu + ((u >> 16) & 1u);   // round-to-nearest-even
  return (unsigned short)(u >> 16);
}

static __device__ __forceinline__ unsigned int pk2(float x, float y) {
  __hip_bfloat162 h = __float22bfloat162_rn(make_float2(x, y));
  return *(unsigned int*)&h;
}

static __device__ __forceinline__ void gld_lds16(const void* g, void* l) {
  __builtin_amdgcn_global_load_lds((const __attribute__((address_space(1))) void*)g,
                                   (__attribute__((address_space(3))) void*)l, 16, 0, 0);
}

// Q pre-scale: 64^-0.5 * log2(e)
#define QSC 0.18033688f

// ---------------------------------------------------------------------------
// prep: fused convert_x + transpose w_qkv + transpose w_proj + zero ticket.
// ---------------------------------------------------------------------------
static __device__ __forceinline__ void transpose_body(
    const float* __restrict__ in, unsigned short* __restrict__ out,
    int R, int C, int bx, int by, int tid) {
  __shared__ float t[32][33];
  const int c0 = bx * 32, r0 = by * 32;
  const int lr = tid >> 3;
  const int lc = (tid & 7) * 4;
  const float* p = in + (size_t)(r0 + lr) * C + c0 + lc;
  float4 v = *(const float4*)p;
  t[lr][lc]     = v.x;
  t[lr][lc + 1] = v.y;
  t[lr][lc + 2] = v.z;
  t[lr][lc + 3] = v.w;
  __syncthreads();
  unsigned short* q = out + (size_t)(c0 + lr) * R + r0 + lc;
  q[0] = f2bf(t[lc][lr]);
  q[1] = f2bf(t[lc + 1][lr]);
  q[2] = f2bf(t[lc + 2][lr]);
  q[3] = f2bf(t[lc + 3][lr]);
}

__global__ __launch_bounds__(256) void prep(
    const float* __restrict__ x, unsigned short* __restrict__ Xb,
    const float* __restrict__ w_qkv, unsigned short* __restrict__ wqkvT,
    const float* __restrict__ w_proj, unsigned short* __restrict__ wprojT,
    int* __restrict__ ticket) {
  const int id = blockIdx.x;
  const int tid = threadIdx.x;
  if (id == 0 && tid == 0) *ticket = 0;   // reset work-steal counter each launch
  if (id < 3072) {
    const int i = (id * 256 + tid) * 8;
    const float4 a0 = *(const float4*)(x + i);
    const float4 a1 = *(const float4*)(x + i + 4);
    union { unsigned int u[4]; u16x8 v; } w;
    w.u[0] = pk2(a0.x, a0.y); w.u[1] = pk2(a0.z, a0.w);
    w.u[2] = pk2(a1.x, a1.y); w.u[3] = pk2(a1.z, a1.w);
    *(u16x8*)(Xb + i) = w.v;
  } else if (id < 4800) {
    const int u = id - 3072;                 // 72 x 24
    transpose_body(w_qkv, wqkvT, MODELD, QKVD, u % 72, u / 72, tid);
  } else {
    const int u = id - 4800;                 // 24 x 24
    transpose_body(w_proj, wprojT, MODELD, MODELD, u % 24, u / 24, tid);
  }
}

// ---------------------------------------------------------------------------
// 4-wave GEMM core (r11, measured ~970 TF while CUs full): BM=BN=128, BK=64,
// 4 waves (2Mx2N), LDS 64KB dbuf -> 2 blocks/CU. Region-staged 2-phase:
//   ph1 reads A(all) + B rows {0-31,64-95}; stages B-late(kt+1) -> buf db^1
//   ph2 reads B rows {32-63,96-127};        stages A(kt+2)+B-early(kt+2) -> db
// ---------------------------------------------------------------------------
#define GEMM_CORE_BODY(AP, BP)                                                 \
  auto stA = [&](int dbuf, int kb, int R) {                                    \
    gld_lds16(AP + (size_t)(R + srow8) * 1536 + kb + scb8,                     \
              (char*)smem + dbuf * 16384 + R * 128);                           \
  };                                                                           \
  auto stB = [&](int dbuf, int kb, int R) {                                    \
    gld_lds16(BP + (size_t)(R + srow8) * 1536 + kb + scb8,                     \
              (char*)smem + 32768 + dbuf * 16384 + R * 128);                   \
  };                                                                           \
  _Pragma("unroll")                                                            \
  for (int pt = 0; pt < 2; ++pt) {                                             \
    const int kb = pt * 128;                                                   \
    stA(pt, kb, wave * 8);      stA(pt, kb, 32 + wave * 8);                    \
    stA(pt, kb, 64 + wave * 8); stA(pt, kb, 96 + wave * 8);                    \
    stB(pt, kb, wave * 8);      stB(pt, kb, 64 + wave * 8);                    \
    stB(pt, kb, 32 + wave * 8); stB(pt, kb, 96 + wave * 8);                    \
  }                                                                            \
  asm volatile("s_waitcnt vmcnt(8)" ::: "memory");                             \
  __builtin_amdgcn_s_barrier();                                                \
  for (int kt = 0; kt < 12; ++kt) {                                            \
    const int db = kt & 1;                                                     \
    const char* Ad = (const char*)smem + db * 16384;                           \
    const char* Bd = (const char*)smem + 32768 + db * 16384;                   \
    bf16x8 a[4][2], b[4][2];                                                   \
    _Pragma("unroll")                                                          \
    for (int i = 0; i < 4; ++i)                                                \
      _Pragma("unroll")                                                        \
      for (int c = 0; c < 2; ++c)                                              \
        a[i][c] = *(const bf16x8*)(Ad + (wm * 64 + i * 16 + fr) * 128 +        \
                                   ((c * 64 + fq * 16) ^ swz));                \
    _Pragma("unroll")                                                          \
    for (int j = 0; j < 2; ++j)                                                \
      _Pragma("unroll")                                                        \
      for (int c = 0; c < 2; ++c)                                              \
        b[j][c] = *(const bf16x8*)(Bd + (wn * 64 + j * 16 + fr) * 128 +        \
                                   ((c * 64 + fq * 16) ^ swz));                \
    if (kt >= 1 && kt <= 10) {                                                 \
      stB(db ^ 1, (kt + 1) * 128, 32 + wave * 8);                              \
      stB(db ^ 1, (kt + 1) * 128, 96 + wave * 8);                              \
    }                                                                          \
    if (kt < 11) asm volatile("s_waitcnt vmcnt(8)" ::: "memory");              \
    else         asm volatile("s_waitcnt vmcnt(0)" ::: "memory");              \
    __builtin_amdgcn_s_barrier();                                              \
    __builtin_amdgcn_s_setprio(1);                                             \
    _Pragma("unroll")                                                          \
    for (int i = 0; i < 4; ++i)                                                \
      _Pragma("unroll")                                                        \
      for (int j = 0; j < 2; ++j)                                              \
        _Pragma("unroll")                                                      \
        for (int c = 0; c < 2; ++c)                                            \
          acc[i][j] = __builtin_amdgcn_mfma_f32_16x16x32_bf16(                 \
              a[i][c], b[j][c], acc[i][j], 0, 0, 0);                           \
    __builtin_amdgcn_s_setprio(0);                                             \
    __builtin_amdgcn_s_barrier();                                              \
    _Pragma("unroll")                                                          \
    for (int j = 0; j < 2; ++j)                                                \
      _Pragma("unroll")                                                        \
      for (int c = 0; c < 2; ++c)                                              \
        b[2 + j][c] = *(const bf16x8*)(Bd + (wn * 64 + (2 + j) * 16 + fr) *    \
                                       128 + ((c * 64 + fq * 16) ^ swz));      \
    if (kt <= 9) {                                                             \
      const int kb2 = (kt + 2) * 128;                                          \
      stA(db, kb2, wave * 8);      stA(db, kb2, 32 + wave * 8);                \
      stA(db, kb2, 64 + wave * 8); stA(db, kb2, 96 + wave * 8);                \
      stB(db, kb2, wave * 8);      stB(db, kb2, 64 + wave * 8);                \
    }                                                                          \
    if (kt <= 9)       asm volatile("s_waitcnt vmcnt(6)" ::: "memory");        \
    else if (kt == 10) asm volatile("s_waitcnt vmcnt(2)" ::: "memory");        \
    else               asm volatile("s_waitcnt vmcnt(0)" ::: "memory");        \
    __builtin_amdgcn_s_barrier();                                              \
    __builtin_amdgcn_s_setprio(1);                                             \
    _Pragma("unroll")                                                          \
    for (int i = 0; i < 4; ++i)                                                \
      _Pragma("unroll")                                                        \
      for (int j = 0; j < 2; ++j)                                              \
        _Pragma("unroll")                                                      \
        for (int c = 0; c < 2; ++c)                                            \
          acc[i][2 + j] = __builtin_amdgcn_mfma_f32_16x16x32_bf16(             \
              a[i][c], b[2 + j][c], acc[i][2 + j], 0, 0, 0);                   \
    __builtin_amdgcn_s_setprio(0);                                             \
    __builtin_amdgcn_s_barrier();                                              \
  }

// ---------------------------------------------------------------------------
// GEMM1: qkv = Xb @ WT^T + b. PERSISTENT work-stealing: 512 blocks loop over
// 1152 tiles via atomicAdd ticket (removes the 2.25->3 round quantization
// tail, ~25% of r14's gemm_qkv wall time).
// ---------------------------------------------------------------------------
__global__ __launch_bounds__(256, 2) void gemm_qkv(
    const unsigned short* __restrict__ Xb, const unsigned short* __restrict__ WT,
    const float* __restrict__ bias,
    unsigned short* __restrict__ Qo, unsigned short* __restrict__ Ko,
    unsigned short* __restrict__ VTo, int* __restrict__ ticket) {
  __shared__ __align__(16) unsigned short smem[32768];  // 64KB
  __shared__ int tk;
  const int tid  = threadIdx.x;
  const int lane = tid & 63;
  const int wave = tid >> 6;
  const int wm = wave >> 1, wn = wave & 1;
  const int fr = lane & 15;
  const int fq = lane >> 4;
  const int swz = (fr & 7) << 4;
  const int srow8 = lane >> 3;
  const int scb8 = (((lane & 7) ^ srow8) << 4);

  for (;;) {
    if (tid == 0) tk = atomicAdd(ticket, 1);
    __syncthreads();
    const int t = tk;
    __syncthreads();                   // tk stable before next overwrite
    if (t >= QKV_TILES) break;

    const int flat = (t & 7) * 144 + (t >> 3);   // XCD-chunked mapping
    const int m0 = (flat / 18) * 128;
    const int n0 = (flat % 18) * 128;
    const char* Ap = (const char*)(Xb + (size_t)m0 * MODELD);
    const char* Bp = (const char*)(WT + (size_t)n0 * MODELD);

    f32x4 acc[4][4] = {};
    GEMM_CORE_BODY(Ap, Bp)

    __builtin_amdgcn_s_barrier();      // LDS reuse guard for V scratch
    const int wr = wm * 64, wc = wn * 64;
    const int s = n0 / MODELD;         // 0=q 1=k 2=v, uniform per tile
    if (s < 2) {
      const float qs = (s == 0) ? QSC : 1.0f;
#pragma unroll
      for (int i = 0; i < 4; ++i) {
#pragma unroll
        for (int j = 0; j < 4; ++j) {
          const int col = n0 + wc + j * 16 + fr;
          const int rem = col - s * MODELD;
          const int h = rem >> 6, d = rem & 63;
          const float bv = bias[col];
#pragma unroll
          for (int r = 0; r < 4; ++r) {
            const int row = m0 + wr + i * 16 + fq * 4 + r;
            const int bb = row >> 10, n = row & 1023;
            const int bh = bb * NHEADS + h;
            const unsigned short val = f2bf((acc[i][j][r] + bv) * qs);
            if (s == 0) Qo[((size_t)bh * SEQ + n) * HDIM + d] = val;
            else        Ko[((size_t)bh * SEQ + n) * HDIM + d] = val;
          }
        }
      }
    } else {
      // ---- V epilogue: per-wave LDS transpose, coalesced 16B stores ----
      unsigned short* T = smem + wave * 4608;        // [64][72] per wave
#pragma unroll
      for (int i = 0; i < 4; ++i) {
#pragma unroll
        for (int j = 0; j < 4; ++j) {
          const int col = n0 + wc + j * 16 + fr;
          const float bv = bias[col];
          const int dl = j * 16 + fr;                // d_local = row in T
          union { unsigned int u[2]; u16x4 v; } pk;
          pk.u[0] = pk2(acc[i][j][0] + bv, acc[i][j][1] + bv);
          pk.u[1] = pk2(acc[i][j][2] + bv, acc[i][j][3] + bv);
          *(u16x4*)&T[dl * 72 + i * 16 + fq * 4] = pk.v;
        }
      }
      asm volatile("s_waitcnt lgkmcnt(0)" ::: "memory");
      const int h  = (n0 + wc - 2 * MODELD) >> 6;    // head, uniform per wave
      const int rowb = m0 + wr;                      // 64 q-rows, one batch
      const int bb = rowb >> 10, nq = rowb & 1023;
      const int bh = bb * NHEADS + h;
      unsigned short* Vb = VTo + ((size_t)bh * HDIM) * SEQ + nq;
#pragma unroll
      for (int u = 0; u < 8; ++u) {
        const int d  = u * 8 + (lane >> 3);
        const int qc = (lane & 7) * 8;
        u16x8 v = *(const u16x8*)&T[d * 72 + qc];
        *(u16x8*)(Vb + (size_t)d * SEQ + qc) = v;
      }
    }
    __syncthreads();                   // all LDS traffic done before next tile
  }
}

// ---------------------------------------------------------------------------
// GEMM2: out = AO @ WT^T + b, fp32 out (static grid: 384 wgs = 0.75 rounds,
// no quantization tail).
// ---------------------------------------------------------------------------
__global__ __launch_bounds__(256, 2) void gemm_proj(
    const unsigned short* __restrict__ A, const unsigned short* __restrict__ WT,
    const float* __restrict__ bias, float* __restrict__ Out) {
  __shared__ __align__(16) unsigned short smem[32768];  // 64KB
  const int tid  = threadIdx.x;
  const int lane = tid & 63;
  const int wave = tid >> 6;
  const int wm = wave >> 1, wn = wave & 1;
  const int fr = lane & 15;
  const int fq = lane >> 4;
  const int swz = (fr & 7) << 4;
  const int srow8 = lane >> 3;
  const int scb8 = (((lane & 7) ^ srow8) << 4);
  int flat = blockIdx.x;                             // 384 wgs, %8==0
  flat = (flat & 7) * 48 + (flat >> 3);
  const int m0 = (flat / 6) * 128;
  const int n0 = (flat % 6) * 128;
  const char* Ap = (const char*)(A  + (size_t)m0 * MODELD);
  const char* Bp = (const char*)(WT + (size_t)n0 * MODELD);

  f32x4 acc[4][4] = {};
  GEMM_CORE_BODY(Ap, Bp)

  const int wr = wm * 64, wc = wn * 64;
#pragma unroll
  for (int i = 0; i < 4; ++i) {
#pragma unroll
    for (int j = 0; j < 4; ++j) {
      const int col = n0 + wc + j * 16 + fr;
      const float bv = bias[col];
#pragma unroll
      for (int r = 0; r < 4; ++r) {
        const int row = m0 + wr + i * 16 + fq * 4 + r;
        Out[(size_t)row * MODELD + col] = acc[i][j][r] + bv;
      }
    }
  }
}

// ---------------------------------------------------------------------------
// Flash attention v6 (unchanged): swapped QK^T, in-register P, no max
// tracking, ones-MFMA row-sum, tri-buffered K/V, counted vmcnt.
// ---------------------------------------------------------------------------
__global__ __launch_bounds__(256, 3) void attn_fused(
    const unsigned short* __restrict__ Q, const unsigned short* __restrict__ K,
    const unsigned short* __restrict__ VT, unsigned short* __restrict__ AO) {
  __shared__ __align__(16) unsigned short smem[24576];  // 48KB

  const int tid  = threadIdx.x;
  const int lane = tid & 63;
  const int wave = tid >> 6;

  const int flat = blockIdx.y * 8 + blockIdx.x;
  const int xcd = flat & 7, j = flat >> 3;
  const int bh = xcd * 12 + (j >> 3);
  const int qb = j & 7;
  const int b = bh / NHEADS, h = bh % NHEADS;
  const int q0 = qb * 128 + wave * 32;

  const unsigned short* Qp = Q  + (size_t)bh * SEQ * HDIM;
  const unsigned short* Kp = K  + (size_t)bh * SEQ * HDIM;
  const unsigned short* Vp = VT + (size_t)bh * HDIM * SEQ;

  const int fr = lane & 15;
  const int fq = lane >> 4;
  const int swz = (fr & 7) << 4;

  bf16x8 qf[2][2];
#pragma unroll
  for (int g = 0; g < 2; ++g)
#pragma unroll
    for (int c = 0; c < 2; ++c)
      qf[g][c] = *(const bf16x8*)(Qp + (size_t)(q0 + g * 16 + fr) * HDIM + c * 32 + fq * 8);

  const int srow_lo = (lane >> 3);
  const int scx = (((lane & 7) ^ srow_lo) << 4);

  f32x4 acc[2][4] = {};
  f32x4 accl[2] = {};
  bf16x8 ones;
#pragma unroll
  for (int i = 0; i < 8; ++i) ones[i] = (short)0x3F80;

  auto stage = [&](int buf, int kv0) {
    const char* Kb = (const char*)Kp + (size_t)kv0 * 128;
    const char* Vb = (const char*)Vp + (size_t)kv0 * 2;
#pragma unroll
    for (int u = 0; u < 2; ++u) {
      const int i = wave * 2 + u;
      const int r0 = i * 8 + srow_lo;
      gld_lds16(Kb + (size_t)r0 * 128  + scx, (char*)smem + buf * 8192 + i * 1024);
      gld_lds16(Vb + (size_t)r0 * 2048 + scx, (char*)smem + 24576 + buf * 8192 + i * 1024);
    }
  };

  stage(0, 0);
  stage(1, 64);

  int cur = 0;
  for (int t = 0; t < SEQ / 64; ++t) {
    if (t < SEQ / 64 - 1) asm volatile("s_waitcnt vmcnt(4)" ::: "memory");
    else                  asm volatile("s_waitcnt vmcnt(0)" ::: "memory");
    __builtin_amdgcn_s_barrier();
    if (t < SEQ / 64 - 2) {
      int sb = cur + 2; if (sb >= 3) sb -= 3;
      stage(sb, (t + 2) * 64);
    }

    const char* Kt = (const char*)smem + cur * 8192;
    const char* Vt = (const char*)smem + 24576 + cur * 8192;

    bf16x8 kf[4][2];
#pragma unroll
    for (int ng = 0; ng < 4; ++ng)
#pragma unroll
      for (int c = 0; c < 2; ++c)
        kf[ng][c] = *(const bf16x8*)(Kt + (ng * 16 + fr) * 128 + ((c * 64 + fq * 16) ^ swz));

    f32x4 S[2][4] = {};
    __builtin_amdgcn_s_setprio(1);
#pragma unroll
    for (int g = 0; g < 2; ++g)
#pragma unroll
      for (int ng = 0; ng < 4; ++ng)
#pragma unroll
        for (int c = 0; c < 2; ++c)
          S[g][ng] = __builtin_amdgcn_mfma_f32_16x16x32_bf16(kf[ng][c], qf[g][c], S[g][ng], 0, 0, 0);
    __builtin_amdgcn_s_setprio(0);

    bf16x8 pf[2][2];
#pragma unroll
    for (int g = 0; g < 2; ++g) {
      unsigned int u[4][2];
#pragma unroll
      for (int ng = 0; ng < 4; ++ng) {
        const float p0 = __builtin_amdgcn_exp2f(S[g][ng][0]);
        const float p1 = __builtin_amdgcn_exp2f(S[g][ng][1]);
        const float p2 = __builtin_amdgcn_exp2f(S[g][ng][2]);
        const float p3 = __builtin_amdgcn_exp2f(S[g][ng][3]);
        u[ng][0] = pk2(p0, p1);
        u[ng][1] = pk2(p2, p3);
      }
#pragma unroll
      for (int c = 0; c < 2; ++c) {
        union { unsigned int w[4]; bf16x8 v; } pp;
#pragma unroll
        for (int d2 = 0; d2 < 2; ++d2) {
          unsigned int e = u[2 * c][d2], o = u[2 * c + 1][d2];
          asm("v_permlane32_swap_b32 %0, %1" : "+v"(e), "+v"(o));
          asm("v_permlane16_swap_b32 %0, %1" : "+v"(e), "+v"(o));
          pp.w[d2] = e;
          pp.w[2 + d2] = o;
        }
        pf[g][c] = pp.v;
      }
    }

    bf16x8 vf[4][2];
#pragma unroll
    for (int df = 0; df < 4; ++df)
#pragma unroll
      for (int c = 0; c < 2; ++c)
        vf[df][c] = *(const bf16x8*)(Vt + (df * 16 + fr) * 128 + ((c * 64 + fq * 16) ^ swz));

    __builtin_amdgcn_s_setprio(1);
#pragma unroll
    for (int g = 0; g < 2; ++g) {
#pragma unroll
      for (int df = 0; df < 4; ++df)
#pragma unroll
        for (int c = 0; c < 2; ++c)
          acc[g][df] = __builtin_amdgcn_mfma_f32_16x16x32_bf16(pf[g][c], vf[df][c], acc[g][df], 0, 0, 0);
#pragma unroll
      for (int c = 0; c < 2; ++c)
        accl[g] = __builtin_amdgcn_mfma_f32_16x16x32_bf16(pf[g][c], ones, accl[g], 0, 0, 0);
    }
    __builtin_amdgcn_s_setprio(0);

    cur = (cur == 2) ? 0 : cur + 1;
  }

#pragma unroll
  for (int g = 0; g < 2; ++g) {
#pragma unroll
    for (int r = 0; r < 4; ++r) {
      const float inv = 1.0f / accl[g][r];
      const int q = q0 + g * 16 + fq * 4 + r;
      unsigned short* outp = AO + ((size_t)b * SEQ + q) * MODELD + h * HDIM;
#pragma unroll
      for (int df = 0; df < 4; ++df)
        outp[df * 16 + fr] = f2bf(acc[g][df][r] * inv);
    }
  }
}

// ---------------------------------------------------------------------------
extern "C" void kernel_launch(void* const* d_in, const int* in_sizes, int n_in,
                              void* d_out, int out_size, void* d_ws, size_t ws_size,
                              hipStream_t stream) {
  const float* x      = (const float*)d_in[0];
  const float* w_qkv  = (const float*)d_in[1];
  const float* b_qkv  = (const float*)d_in[2];
  const float* w_proj = (const float*)d_in[3];
  const float* b_proj = (const float*)d_in[4];
  float* out = (float*)d_out;

  unsigned short* ws = (unsigned short*)d_ws;
  unsigned short* wqkvT  = ws;                               // [2304][768]
  unsigned short* wprojT = wqkvT + (size_t)QKVD * MODELD;    // [768][768]
  unsigned short* Qw     = wprojT + (size_t)MODELD * MODELD; // [96][1024][64]
  unsigned short* Kw     = Qw + (size_t)BHEADS * SEQ * HDIM;
  unsigned short* VTw    = Kw + (size_t)BHEADS * SEQ * HDIM; // [96][64][1024]
  unsigned short* AO     = VTw + (size_t)BHEADS * SEQ * HDIM;// [8192][768]
  unsigned short* Xb     = AO + (size_t)NBATCH * SEQ * MODELD;// [8192][768]
  int* ticket = (int*)(Xb + (size_t)NBATCH * SEQ * MODELD);  // 4B counter

  prep<<<dim3(5376), 256, 0, stream>>>(x, Xb, w_qkv, wqkvT, w_proj, wprojT, ticket);
  gemm_qkv<<<dim3(QKV_BLOCKS), 256, 0, stream>>>(
      Xb, wqkvT, b_qkv, Qw, Kw, VTw, ticket);
  attn_fused<<<dim3(SEQ / 128, BHEADS), 256, 0, stream>>>(Qw, Kw, VTw, AO);
  gemm_proj<<<dim3((MODELD / 128) * ((NBATCH * SEQ) / 128)), 256, 0, stream>>>(
      AO, wprojT, b_proj, out);
}

// Round 16
// 109.953 us; speedup vs baseline: 1.0029x; 1.0029x over previous
//
#include <hip/hip_runtime.h>
#include <hip/hip_bf16.h>

#define NHEADS 12
#define HDIM   64
#define SEQ    1024
#define NBATCH 8
#define MODELD 768
#define QKVD   2304
#define BHEADS (NBATCH * NHEADS)   // 96
#define QKV_BLOCKS 512             // 2 per CU, persistent
#define TILES_PER_GROUP 144        // 8 groups x 144 = 1152 tiles

typedef __attribute__((ext_vector_type(8))) short          bf16x8;
typedef __attribute__((ext_vector_type(8))) unsigned short u16x8;
typedef __attribute__((ext_vector_type(4))) unsigned short u16x4;
typedef __attribute__((ext_vector_type(4))) float          f32x4;

static __device__ __forceinline__ unsigned short f2bf(float f) {
  unsigned int u = __float_as_uint(f);
  u += 0x7fffu + ((u >> 16) & 1u);   // round-to-nearest-even
  return (unsigned short)(u >> 16);
}

static __device__ __forceinline__ unsigned int pk2(float x, float y) {
  __hip_bfloat162 h = __float22bfloat162_rn(make_float2(x, y));
  return *(unsigned int*)&h;
}

static __device__ __forceinline__ void gld_lds16(const void* g, void* l) {
  __builtin_amdgcn_global_load_lds((const __attribute__((address_space(1))) void*)g,
                                   (__attribute__((address_space(3))) void*)l, 16, 0, 0);
}

// Q pre-scale: 64^-0.5 * log2(e)
#define QSC 0.18033688f

// ---------------------------------------------------------------------------
// prep: fused convert_x + transpose w_qkv + transpose w_proj + zero tickets.
// ---------------------------------------------------------------------------
static __device__ __forceinline__ void transpose_body(
    const float* __restrict__ in, unsigned short* __restrict__ out,
    int R, int C, int bx, int by, int tid) {
  __shared__ float t[32][33];
  const int c0 = bx * 32, r0 = by * 32;
  const int lr = tid >> 3;
  const int lc = (tid & 7) * 4;
  const float* p = in + (size_t)(r0 + lr) * C + c0 + lc;
  float4 v = *(const float4*)p;
  t[lr][lc]     = v.x;
  t[lr][lc + 1] = v.y;
  t[lr][lc + 2] = v.z;
  t[lr][lc + 3] = v.w;
  __syncthreads();
  unsigned short* q = out + (size_t)(c0 + lr) * R + r0 + lc;
  q[0] = f2bf(t[lc][lr]);
  q[1] = f2bf(t[lc + 1][lr]);
  q[2] = f2bf(t[lc + 2][lr]);
  q[3] = f2bf(t[lc + 3][lr]);
}

__global__ __launch_bounds__(256) void prep(
    const float* __restrict__ x, unsigned short* __restrict__ Xb,
    const float* __restrict__ w_qkv, unsigned short* __restrict__ wqkvT,
    const float* __restrict__ w_proj, unsigned short* __restrict__ wprojT,
    int* __restrict__ tickets) {
  const int id = blockIdx.x;
  const int tid = threadIdx.x;
  if (id == 0 && tid < 8) tickets[tid] = 0;   // reset group counters
  if (id < 3072) {
    const int i = (id * 256 + tid) * 8;
    const float4 a0 = *(const float4*)(x + i);
    const float4 a1 = *(const float4*)(x + i + 4);
    union { unsigned int u[4]; u16x8 v; } w;
    w.u[0] = pk2(a0.x, a0.y); w.u[1] = pk2(a0.z, a0.w);
    w.u[2] = pk2(a1.x, a1.y); w.u[3] = pk2(a1.z, a1.w);
    *(u16x8*)(Xb + i) = w.v;
  } else if (id < 4800) {
    const int u = id - 3072;                 // 72 x 24
    transpose_body(w_qkv, wqkvT, MODELD, QKVD, u % 72, u / 72, tid);
  } else {
    const int u = id - 4800;                 // 24 x 24
    transpose_body(w_proj, wprojT, MODELD, MODELD, u % 24, u / 24, tid);
  }
}

// ---------------------------------------------------------------------------
// 4-wave GEMM core (r11, measured best): BM=BN=128, BK=64, 4 waves (2Mx2N),
// LDS 64KB dbuf -> 2 blocks/CU. Region-staged 2-phase with counted vmcnt.
// ---------------------------------------------------------------------------
#define GEMM_CORE_BODY(AP, BP)                                                 \
  auto stA = [&](int dbuf, int kb, int R) {                                    \
    gld_lds16(AP + (size_t)(R + srow8) * 1536 + kb + scb8,                     \
              (char*)smem + dbuf * 16384 + R * 128);                           \
  };                                                                           \
  auto stB = [&](int dbuf, int kb, int R) {                                    \
    gld_lds16(BP + (size_t)(R + srow8) * 1536 + kb + scb8,                     \
              (char*)smem + 32768 + dbuf * 16384 + R * 128);                   \
  };                                                                           \
  _Pragma("unroll")                                                            \
  for (int pt = 0; pt < 2; ++pt) {                                             \
    const int kb = pt * 128;                                                   \
    stA(pt, kb, wave * 8);      stA(pt, kb, 32 + wave * 8);                    \
    stA(pt, kb, 64 + wave * 8); stA(pt, kb, 96 + wave * 8);                    \
    stB(pt, kb, wave * 8);      stB(pt, kb, 64 + wave * 8);                    \
    stB(pt, kb, 32 + wave * 8); stB(pt, kb, 96 + wave * 8);                    \
  }                                                                            \
  asm volatile("s_waitcnt vmcnt(8)" ::: "memory");                             \
  __builtin_amdgcn_s_barrier();                                                \
  for (int kt = 0; kt < 12; ++kt) {                                            \
    const int db = kt & 1;                                                     \
    const char* Ad = (const char*)smem + db * 16384;                           \
    const char* Bd = (const char*)smem + 32768 + db * 16384;                   \
    bf16x8 a[4][2], b[4][2];                                                   \
    _Pragma("unroll")                                                          \
    for (int i = 0; i < 4; ++i)                                                \
      _Pragma("unroll")                                                        \
      for (int c = 0; c < 2; ++c)                                              \
        a[i][c] = *(const bf16x8*)(Ad + (wm * 64 + i * 16 + fr) * 128 +        \
                                   ((c * 64 + fq * 16) ^ swz));                \
    _Pragma("unroll")                                                          \
    for (int j = 0; j < 2; ++j)                                                \
      _Pragma("unroll")                                                        \
      for (int c = 0; c < 2; ++c)                                              \
        b[j][c] = *(const bf16x8*)(Bd + (wn * 64 + j * 16 + fr) * 128 +        \
                                   ((c * 64 + fq * 16) ^ swz));                \
    if (kt >= 1 && kt <= 10) {                                                 \
      stB(db ^ 1, (kt + 1) * 128, 32 + wave * 8);                              \
      stB(db ^ 1, (kt + 1) * 128, 96 + wave * 8);                              \
    }                                                                          \
    if (kt < 11) asm volatile("s_waitcnt vmcnt(8)" ::: "memory");              \
    else         asm volatile("s_waitcnt vmcnt(0)" ::: "memory");              \
    __builtin_amdgcn_s_barrier();                                              \
    __builtin_amdgcn_s_setprio(1);                                             \
    _Pragma("unroll")                                                          \
    for (int i = 0; i < 4; ++i)                                                \
      _Pragma("unroll")                                                        \
      for (int j = 0; j < 2; ++j)                                              \
        _Pragma("unroll")                                                      \
        for (int c = 0; c < 2; ++c)                                            \
          acc[i][j] = __builtin_amdgcn_mfma_f32_16x16x32_bf16(                 \
              a[i][c], b[j][c], acc[i][j], 0, 0, 0);                           \
    __builtin_amdgcn_s_setprio(0);                                             \
    __builtin_amdgcn_s_barrier();                                              \
    _Pragma("unroll")                                                          \
    for (int j = 0; j < 2; ++j)                                                \
      _Pragma("unroll")                                                        \
      for (int c = 0; c < 2; ++c)                                              \
        b[2 + j][c] = *(const bf16x8*)(Bd + (wn * 64 + (2 + j) * 16 + fr) *    \
                                       128 + ((c * 64 + fq * 16) ^ swz));      \
    if (kt <= 9) {                                                             \
      const int kb2 = (kt + 2) * 128;                                          \
      stA(db, kb2, wave * 8);      stA(db, kb2, 32 + wave * 8);                \
      stA(db, kb2, 64 + wave * 8); stA(db, kb2, 96 + wave * 8);                \
      stB(db, kb2, wave * 8);      stB(db, kb2, 64 + wave * 8);                \
    }                                                                          \
    if (kt <= 9)       asm volatile("s_waitcnt vmcnt(6)" ::: "memory");        \
    else if (kt == 10) asm volatile("s_waitcnt vmcnt(2)" ::: "memory");        \
    else               asm volatile("s_waitcnt vmcnt(0)" ::: "memory");        \
    __builtin_amdgcn_s_barrier();                                              \
    __builtin_amdgcn_s_setprio(1);                                             \
    _Pragma("unroll")                                                          \
    for (int i = 0; i < 4; ++i)                                                \
      _Pragma("unroll")                                                        \
      for (int j = 0; j < 2; ++j)                                              \
        _Pragma("unroll")                                                      \
        for (int c = 0; c < 2; ++c)                                            \
          acc[i][2 + j] = __builtin_amdgcn_mfma_f32_16x16x32_bf16(             \
              a[i][c], b[2 + j][c], acc[i][2 + j], 0, 0, 0);                   \
    __builtin_amdgcn_s_setprio(0);                                             \
    __builtin_amdgcn_s_barrier();                                              \
  }

// ---------------------------------------------------------------------------
// GEMM1: qkv = Xb @ WT^T + b. Persistent GROUP-LOCAL work-stealing: 512
// blocks; block bid steals only from chunk (bid&7) (its likely XCD, since
// dispatch round-robins XCDs) -> removes the 2.25->3 round tail WITHOUT
// r15's cross-XCD locality loss (FETCH +63% was the regression's cause).
// Within a chunk, consecutive tickets share the A m-panel (L2-hot).
// ---------------------------------------------------------------------------
__global__ __launch_bounds__(256, 2) void gemm_qkv(
    const unsigned short* __restrict__ Xb, const unsigned short* __restrict__ WT,
    const float* __restrict__ bias,
    unsigned short* __restrict__ Qo, unsigned short* __restrict__ Ko,
    unsigned short* __restrict__ VTo, int* __restrict__ tickets) {
  __shared__ __align__(16) unsigned short smem[32768];  // 64KB
  __shared__ int tk;
  const int tid  = threadIdx.x;
  const int lane = tid & 63;
  const int wave = tid >> 6;
  const int wm = wave >> 1, wn = wave & 1;
  const int fr = lane & 15;
  const int fq = lane >> 4;
  const int swz = (fr & 7) << 4;
  const int srow8 = lane >> 3;
  const int scb8 = (((lane & 7) ^ srow8) << 4);
  const int grp = blockIdx.x & 7;

  for (;;) {
    if (tid == 0) tk = atomicAdd(&tickets[grp], 1);
    __syncthreads();
    const int t = tk;
    __syncthreads();                   // tk stable before next overwrite
    if (t >= TILES_PER_GROUP) break;

    const int flat = grp * TILES_PER_GROUP + t;  // same map as static swizzle
    const int m0 = (flat / 18) * 128;
    const int n0 = (flat % 18) * 128;
    const char* Ap = (const char*)(Xb + (size_t)m0 * MODELD);
    const char* Bp = (const char*)(WT + (size_t)n0 * MODELD);

    f32x4 acc[4][4] = {};
    GEMM_CORE_BODY(Ap, Bp)

    __builtin_amdgcn_s_barrier();      // LDS reuse guard for V scratch
    const int wr = wm * 64, wc = wn * 64;
    const int s = n0 / MODELD;         // 0=q 1=k 2=v, uniform per tile
    if (s < 2) {
      const float qs = (s == 0) ? QSC : 1.0f;
#pragma unroll
      for (int i = 0; i < 4; ++i) {
#pragma unroll
        for (int j = 0; j < 4; ++j) {
          const int col = n0 + wc + j * 16 + fr;
          const int rem = col - s * MODELD;
          const int h = rem >> 6, d = rem & 63;
          const float bv = bias[col];
#pragma unroll
          for (int r = 0; r < 4; ++r) {
            const int row = m0 + wr + i * 16 + fq * 4 + r;
            const int bb = row >> 10, n = row & 1023;
            const int bh = bb * NHEADS + h;
            const unsigned short val = f2bf((acc[i][j][r] + bv) * qs);
            if (s == 0) Qo[((size_t)bh * SEQ + n) * HDIM + d] = val;
            else        Ko[((size_t)bh * SEQ + n) * HDIM + d] = val;
          }
        }
      }
    } else {
      // ---- V epilogue: per-wave LDS transpose, coalesced 16B stores ----
      unsigned short* T = smem + wave * 4608;        // [64][72] per wave
#pragma unroll
      for (int i = 0; i < 4; ++i) {
#pragma unroll
        for (int j = 0; j < 4; ++j) {
          const int col = n0 + wc + j * 16 + fr;
          const float bv = bias[col];
          const int dl = j * 16 + fr;                // d_local = row in T
          union { unsigned int u[2]; u16x4 v; } pk;
          pk.u[0] = pk2(acc[i][j][0] + bv, acc[i][j][1] + bv);
          pk.u[1] = pk2(acc[i][j][2] + bv, acc[i][j][3] + bv);
          *(u16x4*)&T[dl * 72 + i * 16 + fq * 4] = pk.v;
        }
      }
      asm volatile("s_waitcnt lgkmcnt(0)" ::: "memory");
      const int h  = (n0 + wc - 2 * MODELD) >> 6;    // head, uniform per wave
      const int rowb = m0 + wr;                      // 64 q-rows, one batch
      const int bb = rowb >> 10, nq = rowb & 1023;
      const int bh = bb * NHEADS + h;
      unsigned short* Vb = VTo + ((size_t)bh * HDIM) * SEQ + nq;
#pragma unroll
      for (int u = 0; u < 8; ++u) {
        const int d  = u * 8 + (lane >> 3);
        const int qc = (lane & 7) * 8;
        u16x8 v = *(const u16x8*)&T[d * 72 + qc];
        *(u16x8*)(Vb + (size_t)d * SEQ + qc) = v;
      }
    }
    __syncthreads();                   // all LDS traffic done before next tile
  }
}

// ---------------------------------------------------------------------------
// GEMM2: out = AO @ WT^T + b, fp32 out (static grid: 384 wgs = 0.75 rounds).
// ---------------------------------------------------------------------------
__global__ __launch_bounds__(256, 2) void gemm_proj(
    const unsigned short* __restrict__ A, const unsigned short* __restrict__ WT,
    const float* __restrict__ bias, float* __restrict__ Out) {
  __shared__ __align__(16) unsigned short smem[32768];  // 64KB
  const int tid  = threadIdx.x;
  const int lane = tid & 63;
  const int wave = tid >> 6;
  const int wm = wave >> 1, wn = wave & 1;
  const int fr = lane & 15;
  const int fq = lane >> 4;
  const int swz = (fr & 7) << 4;
  const int srow8 = lane >> 3;
  const int scb8 = (((lane & 7) ^ srow8) << 4);
  int flat = blockIdx.x;                             // 384 wgs, %8==0
  flat = (flat & 7) * 48 + (flat >> 3);
  const int m0 = (flat / 6) * 128;
  const int n0 = (flat % 6) * 128;
  const char* Ap = (const char*)(A  + (size_t)m0 * MODELD);
  const char* Bp = (const char*)(WT + (size_t)n0 * MODELD);

  f32x4 acc[4][4] = {};
  GEMM_CORE_BODY(Ap, Bp)

  const int wr = wm * 64, wc = wn * 64;
#pragma unroll
  for (int i = 0; i < 4; ++i) {
#pragma unroll
    for (int j = 0; j < 4; ++j) {
      const int col = n0 + wc + j * 16 + fr;
      const float bv = bias[col];
#pragma unroll
      for (int r = 0; r < 4; ++r) {
        const int row = m0 + wr + i * 16 + fq * 4 + r;
        Out[(size_t)row * MODELD + col] = acc[i][j][r] + bv;
      }
    }
  }
}

// ---------------------------------------------------------------------------
// Flash attention v6 (unchanged): swapped QK^T, in-register P, no max
// tracking, ones-MFMA row-sum, tri-buffered K/V, counted vmcnt.
// ---------------------------------------------------------------------------
__global__ __launch_bounds__(256, 3) void attn_fused(
    const unsigned short* __restrict__ Q, const unsigned short* __restrict__ K,
    const unsigned short* __restrict__ VT, unsigned short* __restrict__ AO) {
  __shared__ __align__(16) unsigned short smem[24576];  // 48KB

  const int tid  = threadIdx.x;
  const int lane = tid & 63;
  const int wave = tid >> 6;

  const int flat = blockIdx.y * 8 + blockIdx.x;
  const int xcd = flat & 7, j = flat >> 3;
  const int bh = xcd * 12 + (j >> 3);
  const int qb = j & 7;
  const int b = bh / NHEADS, h = bh % NHEADS;
  const int q0 = qb * 128 + wave * 32;

  const unsigned short* Qp = Q  + (size_t)bh * SEQ * HDIM;
  const unsigned short* Kp = K  + (size_t)bh * SEQ * HDIM;
  const unsigned short* Vp = VT + (size_t)bh * HDIM * SEQ;

  const int fr = lane & 15;
  const int fq = lane >> 4;
  const int swz = (fr & 7) << 4;

  bf16x8 qf[2][2];
#pragma unroll
  for (int g = 0; g < 2; ++g)
#pragma unroll
    for (int c = 0; c < 2; ++c)
      qf[g][c] = *(const bf16x8*)(Qp + (size_t)(q0 + g * 16 + fr) * HDIM + c * 32 + fq * 8);

  const int srow_lo = (lane >> 3);
  const int scx = (((lane & 7) ^ srow_lo) << 4);

  f32x4 acc[2][4] = {};
  f32x4 accl[2] = {};
  bf16x8 ones;
#pragma unroll
  for (int i = 0; i < 8; ++i) ones[i] = (short)0x3F80;

  auto stage = [&](int buf, int kv0) {
    const char* Kb = (const char*)Kp + (size_t)kv0 * 128;
    const char* Vb = (const char*)Vp + (size_t)kv0 * 2;
#pragma unroll
    for (int u = 0; u < 2; ++u) {
      const int i = wave * 2 + u;
      const int r0 = i * 8 + srow_lo;
      gld_lds16(Kb + (size_t)r0 * 128  + scx, (char*)smem + buf * 8192 + i * 1024);
      gld_lds16(Vb + (size_t)r0 * 2048 + scx, (char*)smem + 24576 + buf * 8192 + i * 1024);
    }
  };

  stage(0, 0);
  stage(1, 64);

  int cur = 0;
  for (int t = 0; t < SEQ / 64; ++t) {
    if (t < SEQ / 64 - 1) asm volatile("s_waitcnt vmcnt(4)" ::: "memory");
    else                  asm volatile("s_waitcnt vmcnt(0)" ::: "memory");
    __builtin_amdgcn_s_barrier();
    if (t < SEQ / 64 - 2) {
      int sb = cur + 2; if (sb >= 3) sb -= 3;
      stage(sb, (t + 2) * 64);
    }

    const char* Kt = (const char*)smem + cur * 8192;
    const char* Vt = (const char*)smem + 24576 + cur * 8192;

    bf16x8 kf[4][2];
#pragma unroll
    for (int ng = 0; ng < 4; ++ng)
#pragma unroll
      for (int c = 0; c < 2; ++c)
        kf[ng][c] = *(const bf16x8*)(Kt + (ng * 16 + fr) * 128 + ((c * 64 + fq * 16) ^ swz));

    f32x4 S[2][4] = {};
    __builtin_amdgcn_s_setprio(1);
#pragma unroll
    for (int g = 0; g < 2; ++g)
#pragma unroll
      for (int ng = 0; ng < 4; ++ng)
#pragma unroll
        for (int c = 0; c < 2; ++c)
          S[g][ng] = __builtin_amdgcn_mfma_f32_16x16x32_bf16(kf[ng][c], qf[g][c], S[g][ng], 0, 0, 0);
    __builtin_amdgcn_s_setprio(0);

    bf16x8 pf[2][2];
#pragma unroll
    for (int g = 0; g < 2; ++g) {
      unsigned int u[4][2];
#pragma unroll
      for (int ng = 0; ng < 4; ++ng) {
        const float p0 = __builtin_amdgcn_exp2f(S[g][ng][0]);
        const float p1 = __builtin_amdgcn_exp2f(S[g][ng][1]);
        const float p2 = __builtin_amdgcn_exp2f(S[g][ng][2]);
        const float p3 = __builtin_amdgcn_exp2f(S[g][ng][3]);
        u[ng][0] = pk2(p0, p1);
        u[ng][1] = pk2(p2, p3);
      }
#pragma unroll
      for (int c = 0; c < 2; ++c) {
        union { unsigned int w[4]; bf16x8 v; } pp;
#pragma unroll
        for (int d2 = 0; d2 < 2; ++d2) {
          unsigned int e = u[2 * c][d2], o = u[2 * c + 1][d2];
          asm("v_permlane32_swap_b32 %0, %1" : "+v"(e), "+v"(o));
          asm("v_permlane16_swap_b32 %0, %1" : "+v"(e), "+v"(o));
          pp.w[d2] = e;
          pp.w[2 + d2] = o;
        }
        pf[g][c] = pp.v;
      }
    }

    bf16x8 vf[4][2];
#pragma unroll
    for (int df = 0; df < 4; ++df)
#pragma unroll
      for (int c = 0; c < 2; ++c)
        vf[df][c] = *(const bf16x8*)(Vt + (df * 16 + fr) * 128 + ((c * 64 + fq * 16) ^ swz));

    __builtin_amdgcn_s_setprio(1);
#pragma unroll
    for (int g = 0; g < 2; ++g) {
#pragma unroll
      for (int df = 0; df < 4; ++df)
#pragma unroll
        for (int c = 0; c < 2; ++c)
          acc[g][df] = __builtin_amdgcn_mfma_f32_16x16x32_bf16(pf[g][c], vf[df][c], acc[g][df], 0, 0, 0);
#pragma unroll
      for (int c = 0; c < 2; ++c)
        accl[g] = __builtin_amdgcn_mfma_f32_16x16x32_bf16(pf[g][c], ones, accl[g], 0, 0, 0);
    }
    __builtin_amdgcn_s_setprio(0);

    cur = (cur == 2) ? 0 : cur + 1;
  }

#pragma unroll
  for (int g = 0; g < 2; ++g) {
#pragma unroll
    for (int r = 0; r < 4; ++r) {
      const float inv = 1.0f / accl[g][r];
      const int q = q0 + g * 16 + fq * 4 + r;
      unsigned short* outp = AO + ((size_t)b * SEQ + q) * MODELD + h * HDIM;
#pragma unroll
      for (int df = 0; df < 4; ++df)
        outp[df * 16 + fr] = f2bf(acc[g][df][r] * inv);
    }
  }
}

// ---------------------------------------------------------------------------
extern "C" void kernel_launch(void* const* d_in, const int* in_sizes, int n_in,
                              void* d_out, int out_size, void* d_ws, size_t ws_size,
                              hipStream_t stream) {
  const float* x      = (const float*)d_in[0];
  const float* w_qkv  = (const float*)d_in[1];
  const float* b_qkv  = (const float*)d_in[2];
  const float* w_proj = (const float*)d_in[3];
  const float* b_proj = (const float*)d_in[4];
  float* out = (float*)d_out;

  unsigned short* ws = (unsigned short*)d_ws;
  unsigned short* wqkvT  = ws;                               // [2304][768]
  unsigned short* wprojT = wqkvT + (size_t)QKVD * MODELD;    // [768][768]
  unsigned short* Qw     = wprojT + (size_t)MODELD * MODELD; // [96][1024][64]
  unsigned short* Kw     = Qw + (size_t)BHEADS * SEQ * HDIM;
  unsigned short* VTw    = Kw + (size_t)BHEADS * SEQ * HDIM; // [96][64][1024]
  unsigned short* AO     = VTw + (size_t)BHEADS * SEQ * HDIM;// [8192][768]
  unsigned short* Xb     = AO + (size_t)NBATCH * SEQ * MODELD;// [8192][768]
  int* tickets = (int*)(Xb + (size_t)NBATCH * SEQ * MODELD); // 8 x 4B counters

  prep<<<dim3(5376), 256, 0, stream>>>(x, Xb, w_qkv, wqkvT, w_proj, wprojT, tickets);
  gemm_qkv<<<dim3(QKV_BLOCKS), 256, 0, stream>>>(
      Xb, wqkvT, b_qkv, Qw, Kw, VTw, tickets);
  attn_fused<<<dim3(SEQ / 128, BHEADS), 256, 0, stream>>>(Qw, Kw, VTw, AO);
  gemm_proj<<<dim3((MODELD / 128) * ((NBATCH * SEQ) / 128)), 256, 0, stream>>>(
      AO, wprojT, b_proj, out);
}

// Round 17
// 94.412 us; speedup vs baseline: 1.1679x; 1.1646x over previous
//
#include <hip/hip_runtime.h>
#include <hip/hip_bf16.h>

#define NHEADS 12
#define HDIM   64
#define SEQ    1024
#define NBATCH 8
#define MODELD 768
#define QKVD   2304
#define BHEADS (NBATCH * NHEADS)   // 96

typedef __attribute__((ext_vector_type(8))) short          bf16x8;
typedef __attribute__((ext_vector_type(8))) unsigned short u16x8;
typedef __attribute__((ext_vector_type(4))) unsigned short u16x4;
typedef __attribute__((ext_vector_type(4))) float          f32x4;

static __device__ __forceinline__ unsigned short f2bf(float f) {
  unsigned int u = __float_as_uint(f);
  u += 0x7fffu + ((u >> 16) & 1u);   // round-to-nearest-even
  return (unsigned short)(u >> 16);
}

static __device__ __forceinline__ unsigned int pk2(float x, float y) {
  __hip_bfloat162 h = __float22bfloat162_rn(make_float2(x, y));
  return *(unsigned int*)&h;
}

static __device__ __forceinline__ void gld_lds16(const void* g, void* l) {
  __builtin_amdgcn_global_load_lds((const __attribute__((address_space(1))) void*)g,
                                   (__attribute__((address_space(3))) void*)l, 16, 0, 0);
}

// Q pre-scale: 64^-0.5 * log2(e)
#define QSC 0.18033688f

// ---------------------------------------------------------------------------
// prep: fused convert_x + transpose w_qkv + transpose w_proj.
// ---------------------------------------------------------------------------
static __device__ __forceinline__ void transpose_body(
    const float* __restrict__ in, unsigned short* __restrict__ out,
    int R, int C, int bx, int by, int tid) {
  __shared__ float t[32][33];
  const int c0 = bx * 32, r0 = by * 32;
  const int lr = tid >> 3;
  const int lc = (tid & 7) * 4;
  const float* p = in + (size_t)(r0 + lr) * C + c0 + lc;
  float4 v = *(const float4*)p;
  t[lr][lc]     = v.x;
  t[lr][lc + 1] = v.y;
  t[lr][lc + 2] = v.z;
  t[lr][lc + 3] = v.w;
  __syncthreads();
  unsigned short* q = out + (size_t)(c0 + lr) * R + r0 + lc;
  q[0] = f2bf(t[lc][lr]);
  q[1] = f2bf(t[lc + 1][lr]);
  q[2] = f2bf(t[lc + 2][lr]);
  q[3] = f2bf(t[lc + 3][lr]);
}

__global__ __launch_bounds__(256) void prep(
    const float* __restrict__ x, unsigned short* __restrict__ Xb,
    const float* __restrict__ w_qkv, unsigned short* __restrict__ wqkvT,
    const float* __restrict__ w_proj, unsigned short* __restrict__ wprojT) {
  const int id = blockIdx.x;
  const int tid = threadIdx.x;
  if (id < 3072) {
    const int i = (id * 256 + tid) * 8;
    const float4 a0 = *(const float4*)(x + i);
    const float4 a1 = *(const float4*)(x + i + 4);
    union { unsigned int u[4]; u16x8 v; } w;
    w.u[0] = pk2(a0.x, a0.y); w.u[1] = pk2(a0.z, a0.w);
    w.u[2] = pk2(a1.x, a1.y); w.u[3] = pk2(a1.z, a1.w);
    *(u16x8*)(Xb + i) = w.v;
  } else if (id < 4800) {
    const int u = id - 3072;                 // 72 x 24
    transpose_body(w_qkv, wqkvT, MODELD, QKVD, u % 72, u / 72, tid);
  } else {
    const int u = id - 4800;                 // 24 x 24
    transpose_body(w_proj, wprojT, MODELD, MODELD, u % 24, u / 24, tid);
  }
}

// ---------------------------------------------------------------------------
// 4-wave GEMM core (r11, measured best: ~736 TF avg incl. tail): BM=BN=128,
// BK=64, 4 waves (2Mx2N, 64x64/wave), LDS 64KB dbuf -> 2 blocks/CU.
// Region-staged 2-phase:
//   ph1 reads A(all) + B rows {0-31,64-95}; stages B-late(kt+1) -> buf db^1
//   ph2 reads B rows {32-63,96-127};        stages A(kt+2)+B-early(kt+2) -> db
// vmcnt ledger (8 stage calls/wave/iter): ph2 vmcnt(6) is the gate.
// ---------------------------------------------------------------------------
#define GEMM_CORE(AP, BP)                                                      \
  const int tid  = threadIdx.x;                                                \
  const int lane = tid & 63;                                                   \
  const int wave = tid >> 6;                                                   \
  const int wm = wave >> 1, wn = wave & 1;                                     \
  const int fr = lane & 15;                                                    \
  const int fq = lane >> 4;                                                    \
  const int swz = (fr & 7) << 4;                                               \
  const int srow8 = lane >> 3;                                                 \
  const int scb8 = (((lane & 7) ^ srow8) << 4);                                \
  f32x4 acc[4][4] = {};                                                        \
  auto stA = [&](int dbuf, int kb, int R) {                                    \
    gld_lds16(AP + (size_t)(R + srow8) * 1536 + kb + scb8,                     \
              (char*)smem + dbuf * 16384 + R * 128);                           \
  };                                                                           \
  auto stB = [&](int dbuf, int kb, int R) {                                    \
    gld_lds16(BP + (size_t)(R + srow8) * 1536 + kb + scb8,                     \
              (char*)smem + 32768 + dbuf * 16384 + R * 128);                   \
  };                                                                           \
  _Pragma("unroll")                                                            \
  for (int pt = 0; pt < 2; ++pt) {                                             \
    const int kb = pt * 128;                                                   \
    stA(pt, kb, wave * 8);      stA(pt, kb, 32 + wave * 8);                    \
    stA(pt, kb, 64 + wave * 8); stA(pt, kb, 96 + wave * 8);                    \
    stB(pt, kb, wave * 8);      stB(pt, kb, 64 + wave * 8);                    \
    stB(pt, kb, 32 + wave * 8); stB(pt, kb, 96 + wave * 8);                    \
  }                                                                            \
  asm volatile("s_waitcnt vmcnt(8)" ::: "memory");                             \
  __builtin_amdgcn_s_barrier();                                                \
  for (int kt = 0; kt < 12; ++kt) {                                            \
    const int db = kt & 1;                                                     \
    const char* Ad = (const char*)smem + db * 16384;                           \
    const char* Bd = (const char*)smem + 32768 + db * 16384;                   \
    bf16x8 a[4][2], b[4][2];                                                   \
    _Pragma("unroll")                                                          \
    for (int i = 0; i < 4; ++i)                                                \
      _Pragma("unroll")                                                        \
      for (int c = 0; c < 2; ++c)                                              \
        a[i][c] = *(const bf16x8*)(Ad + (wm * 64 + i * 16 + fr) * 128 +        \
                                   ((c * 64 + fq * 16) ^ swz));                \
    _Pragma("unroll")                                                          \
    for (int j = 0; j < 2; ++j)                                                \
      _Pragma("unroll")                                                        \
      for (int c = 0; c < 2; ++c)                                              \
        b[j][c] = *(const bf16x8*)(Bd + (wn * 64 + j * 16 + fr) * 128 +        \
                                   ((c * 64 + fq * 16) ^ swz));                \
    if (kt >= 1 && kt <= 10) {                                                 \
      stB(db ^ 1, (kt + 1) * 128, 32 + wave * 8);                              \
      stB(db ^ 1, (kt + 1) * 128, 96 + wave * 8);                              \
    }                                                                          \
    if (kt < 11) asm volatile("s_waitcnt vmcnt(8)" ::: "memory");              \
    else         asm volatile("s_waitcnt vmcnt(0)" ::: "memory");              \
    __builtin_amdgcn_s_barrier();                                              \
    __builtin_amdgcn_s_setprio(1);                                             \
    _Pragma("unroll")                                                          \
    for (int i = 0; i < 4; ++i)                                                \
      _Pragma("unroll")                                                        \
      for (int j = 0; j < 2; ++j)                                              \
        _Pragma("unroll")                                                      \
        for (int c = 0; c < 2; ++c)                                            \
          acc[i][j] = __builtin_amdgcn_mfma_f32_16x16x32_bf16(                 \
              a[i][c], b[j][c], acc[i][j], 0, 0, 0);                           \
    __builtin_amdgcn_s_setprio(0);                                             \
    __builtin_amdgcn_s_barrier();                                              \
    _Pragma("unroll")                                                          \
    for (int j = 0; j < 2; ++j)                                                \
      _Pragma("unroll")                                                        \
      for (int c = 0; c < 2; ++c)                                              \
        b[2 + j][c] = *(const bf16x8*)(Bd + (wn * 64 + (2 + j) * 16 + fr) *    \
                                       128 + ((c * 64 + fq * 16) ^ swz));      \
    if (kt <= 9) {                                                             \
      const int kb2 = (kt + 2) * 128;                                          \
      stA(db, kb2, wave * 8);      stA(db, kb2, 32 + wave * 8);                \
      stA(db, kb2, 64 + wave * 8); stA(db, kb2, 96 + wave * 8);                \
      stB(db, kb2, wave * 8);      stB(db, kb2, 64 + wave * 8);                \
    }                                                                          \
    if (kt <= 9)       asm volatile("s_waitcnt vmcnt(6)" ::: "memory");        \
    else if (kt == 10) asm volatile("s_waitcnt vmcnt(2)" ::: "memory");        \
    else               asm volatile("s_waitcnt vmcnt(0)" ::: "memory");        \
    __builtin_amdgcn_s_barrier();                                              \
    __builtin_amdgcn_s_setprio(1);                                             \
    _Pragma("unroll")                                                          \
    for (int i = 0; i < 4; ++i)                                                \
      _Pragma("unroll")                                                        \
      for (int j = 0; j < 2; ++j)                                              \
        _Pragma("unroll")                                                      \
        for (int c = 0; c < 2; ++c)                                            \
          acc[i][2 + j] = __builtin_amdgcn_mfma_f32_16x16x32_bf16(             \
              a[i][c], b[2 + j][c], acc[i][2 + j], 0, 0, 0);                   \
    __builtin_amdgcn_s_setprio(0);                                             \
    __builtin_amdgcn_s_barrier();                                              \
  }

// ---------------------------------------------------------------------------
// GEMM1: qkv = Xb @ WT^T + b (static 1152 wgs, 256 thr, 2 blocks/CU).
// Epilogue: Q (pre-scaled by QSC) / K direct; V via per-wave LDS transpose.
// ---------------------------------------------------------------------------
__global__ __launch_bounds__(256, 2) void gemm_qkv(
    const unsigned short* __restrict__ Xb, const unsigned short* __restrict__ WT,
    const float* __restrict__ bias,
    unsigned short* __restrict__ Qo, unsigned short* __restrict__ Ko,
    unsigned short* __restrict__ VTo) {
  __shared__ __align__(16) unsigned short smem[32768];  // 64KB
  int flat = blockIdx.x;                             // 1152 wgs, %8==0
  flat = (flat & 7) * 144 + (flat >> 3);             // XCD-chunked swizzle
  const int m0 = (flat / 18) * 128;
  const int n0 = (flat % 18) * 128;
  const char* Ap = (const char*)(Xb + (size_t)m0 * MODELD);
  const char* Bp = (const char*)(WT + (size_t)n0 * MODELD);

  GEMM_CORE(Ap, Bp)

  __builtin_amdgcn_s_barrier();       // LDS reuse guard for V scratch
  const int wr = wm * 64, wc = wn * 64;
  const int s = n0 / MODELD;          // 0=q 1=k 2=v, uniform per block
  if (s < 2) {
    const float qs = (s == 0) ? QSC : 1.0f;
#pragma unroll
    for (int i = 0; i < 4; ++i) {
#pragma unroll
      for (int j = 0; j < 4; ++j) {
        const int col = n0 + wc + j * 16 + fr;
        const int rem = col - s * MODELD;
        const int h = rem >> 6, d = rem & 63;
        const float bv = bias[col];
#pragma unroll
        for (int r = 0; r < 4; ++r) {
          const int row = m0 + wr + i * 16 + fq * 4 + r;
          const int bb = row >> 10, n = row & 1023;
          const int bh = bb * NHEADS + h;
          const unsigned short val = f2bf((acc[i][j][r] + bv) * qs);
          if (s == 0) Qo[((size_t)bh * SEQ + n) * HDIM + d] = val;
          else        Ko[((size_t)bh * SEQ + n) * HDIM + d] = val;
        }
      }
    }
  } else {
    // ---- V epilogue: per-wave LDS transpose, coalesced 16B stores ----
    unsigned short* T = smem + wave * 4608;          // [64][72] per wave
#pragma unroll
    for (int i = 0; i < 4; ++i) {
#pragma unroll
      for (int j = 0; j < 4; ++j) {
        const int col = n0 + wc + j * 16 + fr;
        const float bv = bias[col];
        const int dl = j * 16 + fr;                  // d_local = row in T
        union { unsigned int u[2]; u16x4 v; } pk;
        pk.u[0] = pk2(acc[i][j][0] + bv, acc[i][j][1] + bv);
        pk.u[1] = pk2(acc[i][j][2] + bv, acc[i][j][3] + bv);
        *(u16x4*)&T[dl * 72 + i * 16 + fq * 4] = pk.v;
      }
    }
    asm volatile("s_waitcnt lgkmcnt(0)" ::: "memory");
    const int h  = (n0 + wc - 2 * MODELD) >> 6;      // head, uniform per wave
    const int rowb = m0 + wr;                        // 64 q-rows, one batch
    const int bb = rowb >> 10, nq = rowb & 1023;
    const int bh = bb * NHEADS + h;
    unsigned short* Vb = VTo + ((size_t)bh * HDIM) * SEQ + nq;
#pragma unroll
    for (int u = 0; u < 8; ++u) {
      const int d  = u * 8 + (lane >> 3);
      const int qc = (lane & 7) * 8;
      u16x8 v = *(const u16x8*)&T[d * 72 + qc];
      *(u16x8*)(Vb + (size_t)d * SEQ + qc) = v;
    }
  }
}

// ---------------------------------------------------------------------------
// GEMM2: out = AO @ WT^T + b, fp32 out.
// ---------------------------------------------------------------------------
__global__ __launch_bounds__(256, 2) void gemm_proj(
    const unsigned short* __restrict__ A, const unsigned short* __restrict__ WT,
    const float* __restrict__ bias, float* __restrict__ Out) {
  __shared__ __align__(16) unsigned short smem[32768];  // 64KB
  int flat = blockIdx.x;                             // 384 wgs, %8==0
  flat = (flat & 7) * 48 + (flat >> 3);
  const int m0 = (flat / 6) * 128;
  const int n0 = (flat % 6) * 128;
  const char* Ap = (const char*)(A  + (size_t)m0 * MODELD);
  const char* Bp = (const char*)(WT + (size_t)n0 * MODELD);

  GEMM_CORE(Ap, Bp)

  const int wr = wm * 64, wc = wn * 64;
#pragma unroll
  for (int i = 0; i < 4; ++i) {
#pragma unroll
    for (int j = 0; j < 4; ++j) {
      const int col = n0 + wc + j * 16 + fr;
      const float bv = bias[col];
#pragma unroll
      for (int r = 0; r < 4; ++r) {
        const int row = m0 + wr + i * 16 + fq * 4 + r;
        Out[(size_t)row * MODELD + col] = acc[i][j][r] + bv;
      }
    }
  }
}

// ---------------------------------------------------------------------------
// Flash attention v6: swapped QK^T, in-register P (T12 permlane), no max
// tracking (Q pre-scaled; pow2-shift invariance), ones-MFMA row-sum,
// tri-buffered K/V with counted vmcnt, one barrier per tile.
// ---------------------------------------------------------------------------
__global__ __launch_bounds__(256, 3) void attn_fused(
    const unsigned short* __restrict__ Q, const unsigned short* __restrict__ K,
    const unsigned short* __restrict__ VT, unsigned short* __restrict__ AO) {
  __shared__ __align__(16) unsigned short smem[24576];  // 48KB

  const int tid  = threadIdx.x;
  const int lane = tid & 63;
  const int wave = tid >> 6;

  const int flat = blockIdx.y * 8 + blockIdx.x;
  const int xcd = flat & 7, j = flat >> 3;
  const int bh = xcd * 12 + (j >> 3);
  const int qb = j & 7;
  const int b = bh / NHEADS, h = bh % NHEADS;
  const int q0 = qb * 128 + wave * 32;

  const unsigned short* Qp = Q  + (size_t)bh * SEQ * HDIM;
  const unsigned short* Kp = K  + (size_t)bh * SEQ * HDIM;
  const unsigned short* Vp = VT + (size_t)bh * HDIM * SEQ;

  const int fr = lane & 15;
  const int fq = lane >> 4;
  const int swz = (fr & 7) << 4;

  bf16x8 qf[2][2];
#pragma unroll
  for (int g = 0; g < 2; ++g)
#pragma unroll
    for (int c = 0; c < 2; ++c)
      qf[g][c] = *(const bf16x8*)(Qp + (size_t)(q0 + g * 16 + fr) * HDIM + c * 32 + fq * 8);

  const int srow_lo = (lane >> 3);
  const int scx = (((lane & 7) ^ srow_lo) << 4);

  f32x4 acc[2][4] = {};
  f32x4 accl[2] = {};
  bf16x8 ones;
#pragma unroll
  for (int i = 0; i < 8; ++i) ones[i] = (short)0x3F80;

  auto stage = [&](int buf, int kv0) {
    const char* Kb = (const char*)Kp + (size_t)kv0 * 128;
    const char* Vb = (const char*)Vp + (size_t)kv0 * 2;
#pragma unroll
    for (int u = 0; u < 2; ++u) {
      const int i = wave * 2 + u;
      const int r0 = i * 8 + srow_lo;
      gld_lds16(Kb + (size_t)r0 * 128  + scx, (char*)smem + buf * 8192 + i * 1024);
      gld_lds16(Vb + (size_t)r0 * 2048 + scx, (char*)smem + 24576 + buf * 8192 + i * 1024);
    }
  };

  stage(0, 0);
  stage(1, 64);

  int cur = 0;
  for (int t = 0; t < SEQ / 64; ++t) {
    if (t < SEQ / 64 - 1) asm volatile("s_waitcnt vmcnt(4)" ::: "memory");
    else                  asm volatile("s_waitcnt vmcnt(0)" ::: "memory");
    __builtin_amdgcn_s_barrier();
    if (t < SEQ / 64 - 2) {
      int sb = cur + 2; if (sb >= 3) sb -= 3;
      stage(sb, (t + 2) * 64);
    }

    const char* Kt = (const char*)smem + cur * 8192;
    const char* Vt = (const char*)smem + 24576 + cur * 8192;

    bf16x8 kf[4][2];
#pragma unroll
    for (int ng = 0; ng < 4; ++ng)
#pragma unroll
      for (int c = 0; c < 2; ++c)
        kf[ng][c] = *(const bf16x8*)(Kt + (ng * 16 + fr) * 128 + ((c * 64 + fq * 16) ^ swz));

    f32x4 S[2][4] = {};
    __builtin_amdgcn_s_setprio(1);
#pragma unroll
    for (int g = 0; g < 2; ++g)
#pragma unroll
      for (int ng = 0; ng < 4; ++ng)
#pragma unroll
        for (int c = 0; c < 2; ++c)
          S[g][ng] = __builtin_amdgcn_mfma_f32_16x16x32_bf16(kf[ng][c], qf[g][c], S[g][ng], 0, 0, 0);
    __builtin_amdgcn_s_setprio(0);

    bf16x8 pf[2][2];
#pragma unroll
    for (int g = 0; g < 2; ++g) {
      unsigned int u[4][2];
#pragma unroll
      for (int ng = 0; ng < 4; ++ng) {
        const float p0 = __builtin_amdgcn_exp2f(S[g][ng][0]);
        const float p1 = __builtin_amdgcn_exp2f(S[g][ng][1]);
        const float p2 = __builtin_amdgcn_exp2f(S[g][ng][2]);
        const float p3 = __builtin_amdgcn_exp2f(S[g][ng][3]);
        u[ng][0] = pk2(p0, p1);
        u[ng][1] = pk2(p2, p3);
      }
#pragma unroll
      for (int c = 0; c < 2; ++c) {
        union { unsigned int w[4]; bf16x8 v; } pp;
#pragma unroll
        for (int d2 = 0; d2 < 2; ++d2) {
          unsigned int e = u[2 * c][d2], o = u[2 * c + 1][d2];
          asm("v_permlane32_swap_b32 %0, %1" : "+v"(e), "+v"(o));
          asm("v_permlane16_swap_b32 %0, %1" : "+v"(e), "+v"(o));
          pp.w[d2] = e;
          pp.w[2 + d2] = o;
        }
        pf[g][c] = pp.v;
      }
    }

    bf16x8 vf[4][2];
#pragma unroll
    for (int df = 0; df < 4; ++df)
#pragma unroll
      for (int c = 0; c < 2; ++c)
        vf[df][c] = *(const bf16x8*)(Vt + (df * 16 + fr) * 128 + ((c * 64 + fq * 16) ^ swz));

    __builtin_amdgcn_s_setprio(1);
#pragma unroll
    for (int g = 0; g < 2; ++g) {
#pragma unroll
      for (int df = 0; df < 4; ++df)
#pragma unroll
        for (int c = 0; c < 2; ++c)
          acc[g][df] = __builtin_amdgcn_mfma_f32_16x16x32_bf16(pf[g][c], vf[df][c], acc[g][df], 0, 0, 0);
#pragma unroll
      for (int c = 0; c < 2; ++c)
        accl[g] = __builtin_amdgcn_mfma_f32_16x16x32_bf16(pf[g][c], ones, accl[g], 0, 0, 0);
    }
    __builtin_amdgcn_s_setprio(0);

    cur = (cur == 2) ? 0 : cur + 1;
  }

#pragma unroll
  for (int g = 0; g < 2; ++g) {
#pragma unroll
    for (int r = 0; r < 4; ++r) {
      const float inv = 1.0f / accl[g][r];
      const int q = q0 + g * 16 + fq * 4 + r;
      unsigned short* outp = AO + ((size_t)b * SEQ + q) * MODELD + h * HDIM;
#pragma unroll
      for (int df = 0; df < 4; ++df)
        outp[df * 16 + fr] = f2bf(acc[g][df][r] * inv);
    }
  }
}

// ---------------------------------------------------------------------------
extern "C" void kernel_launch(void* const* d_in, const int* in_sizes, int n_in,
                              void* d_out, int out_size, void* d_ws, size_t ws_size,
                              hipStream_t stream) {
  const float* x      = (const float*)d_in[0];
  const float* w_qkv  = (const float*)d_in[1];
  const float* b_qkv  = (const float*)d_in[2];
  const float* w_proj = (const float*)d_in[3];
  const float* b_proj = (const float*)d_in[4];
  float* out = (float*)d_out;

  unsigned short* ws = (unsigned short*)d_ws;
  unsigned short* wqkvT  = ws;                               // [2304][768]
  unsigned short* wprojT = wqkvT + (size_t)QKVD * MODELD;    // [768][768]
  unsigned short* Qw     = wprojT + (size_t)MODELD * MODELD; // [96][1024][64]
  unsigned short* Kw     = Qw + (size_t)BHEADS * SEQ * HDIM;
  unsigned short* VTw    = Kw + (size_t)BHEADS * SEQ * HDIM; // [96][64][1024]
  unsigned short* AO     = VTw + (size_t)BHEADS * SEQ * HDIM;// [8192][768]
  unsigned short* Xb     = AO + (size_t)NBATCH * SEQ * MODELD;// [8192][768]

  prep<<<dim3(5376), 256, 0, stream>>>(x, Xb, w_qkv, wqkvT, w_proj, wprojT);
  gemm_qkv<<<dim3((QKVD / 128) * ((NBATCH * SEQ) / 128)), 256, 0, stream>>>(
      Xb, wqkvT, b_qkv, Qw, Kw, VTw);
  attn_fused<<<dim3(SEQ / 128, BHEADS), 256, 0, stream>>>(Qw, Kw, VTw, AO);
  gemm_proj<<<dim3((MODELD / 128) * ((NBATCH * SEQ) / 128)), 256, 0, stream>>>(
      AO, wprojT, b_proj, out);
}

// Round 18
// 93.534 us; speedup vs baseline: 1.1789x; 1.0094x over previous
//
#include <hip/hip_runtime.h>
#include <hip/hip_bf16.h>

#define NHEADS 12
#define HDIM   64
#define SEQ    1024
#define NBATCH 8
#define MODELD 768
#define QKVD   2304
#define BHEADS (NBATCH * NHEADS)   // 96

typedef __attribute__((ext_vector_type(8))) short          bf16x8;
typedef __attribute__((ext_vector_type(8))) unsigned short u16x8;
typedef __attribute__((ext_vector_type(4))) unsigned short u16x4;
typedef __attribute__((ext_vector_type(4))) float          f32x4;

static __device__ __forceinline__ unsigned short f2bf(float f) {
  unsigned int u = __float_as_uint(f);
  u += 0x7fffu + ((u >> 16) & 1u);   // round-to-nearest-even
  return (unsigned short)(u >> 16);
}

static __device__ __forceinline__ unsigned int pk2(float x, float y) {
  __hip_bfloat162 h = __float22bfloat162_rn(make_float2(x, y));
  return *(unsigned int*)&h;
}

static __device__ __forceinline__ void gld_lds16(const void* g, void* l) {
  __builtin_amdgcn_global_load_lds((const __attribute__((address_space(1))) void*)g,
                                   (__attribute__((address_space(3))) void*)l, 16, 0, 0);
}

// Q pre-scale: 64^-0.5 * log2(e)
#define QSC 0.18033688f

// ---------------------------------------------------------------------------
// prep: fused convert_x + transpose w_qkv + transpose w_proj.
// ---------------------------------------------------------------------------
static __device__ __forceinline__ void transpose_body(
    const float* __restrict__ in, unsigned short* __restrict__ out,
    int R, int C, int bx, int by, int tid) {
  __shared__ float t[32][33];
  const int c0 = bx * 32, r0 = by * 32;
  const int lr = tid >> 3;
  const int lc = (tid & 7) * 4;
  const float* p = in + (size_t)(r0 + lr) * C + c0 + lc;
  float4 v = *(const float4*)p;
  t[lr][lc]     = v.x;
  t[lr][lc + 1] = v.y;
  t[lr][lc + 2] = v.z;
  t[lr][lc + 3] = v.w;
  __syncthreads();
  unsigned short* q = out + (size_t)(c0 + lr) * R + r0 + lc;
  q[0] = f2bf(t[lc][lr]);
  q[1] = f2bf(t[lc + 1][lr]);
  q[2] = f2bf(t[lc + 2][lr]);
  q[3] = f2bf(t[lc + 3][lr]);
}

__global__ __launch_bounds__(256) void prep(
    const float* __restrict__ x, unsigned short* __restrict__ Xb,
    const float* __restrict__ w_qkv, unsigned short* __restrict__ wqkvT,
    const float* __restrict__ w_proj, unsigned short* __restrict__ wprojT) {
  const int id = blockIdx.x;
  const int tid = threadIdx.x;
  if (id < 3072) {
    const int i = (id * 256 + tid) * 8;
    const float4 a0 = *(const float4*)(x + i);
    const float4 a1 = *(const float4*)(x + i + 4);
    union { unsigned int u[4]; u16x8 v; } w;
    w.u[0] = pk2(a0.x, a0.y); w.u[1] = pk2(a0.z, a0.w);
    w.u[2] = pk2(a1.x, a1.y); w.u[3] = pk2(a1.z, a1.w);
    *(u16x8*)(Xb + i) = w.v;
  } else if (id < 4800) {
    const int u = id - 3072;                 // 72 x 24
    transpose_body(w_qkv, wqkvT, MODELD, QKVD, u % 72, u / 72, tid);
  } else {
    const int u = id - 4800;                 // 24 x 24
    transpose_body(w_proj, wprojT, MODELD, MODELD, u % 24, u / 24, tid);
  }
}

// ---------------------------------------------------------------------------
// 4-wave GEMM core, BM=128 BN=96 BK=64 (tail-free grids: qkv 1536 = 3x512,
// proj 512 = 1x512 exactly). LDS 56KB dbuf -> 2 blocks/CU. Region-staged
// 2-phase (r11 scheme rescaled):
//   ph1 reads A(all rows) + B rows {0-31, 48-79} (j=0,1); stages Bl(kt+1) [1]
//   ph2 reads B rows {32-47, 80-95} (j=2);         stages A+Be(kt+2)   [6]
// vmcnt ledger (7 calls/wave/iter): ph2 vmcnt(6) keeps only its own 6 =>
// tile kt+1 fully landed; prologue 14 -> vmcnt(7); tail kt=10 -> vmcnt(1).
// A bufs @ 0/16384; B bufs @ 32768 / 45056 (12KB each).
// ---------------------------------------------------------------------------
#define GEMM_CORE96(AP, BP)                                                    \
  const int tid  = threadIdx.x;                                                \
  const int lane = tid & 63;                                                   \
  const int wave = tid >> 6;                                                   \
  const int wm = wave >> 1, wn = wave & 1;                                     \
  const int fr = lane & 15;                                                    \
  const int fq = lane >> 4;                                                    \
  const int swz = (fr & 7) << 4;                                               \
  const int srow8 = lane >> 3;                                                 \
  const int scb8 = (((lane & 7) ^ srow8) << 4);                                \
  const int ReB0 = wave * 8;            /* B-early chunks 0-3   */             \
  const int ReB1 = 48 + wave * 8;       /* B-early chunks 6-9   */             \
  const int RlB  = ((wave & 2) ? 64 : 32) + wave * 8; /* late 4,5,10,11 */     \
  f32x4 acc[4][3] = {};                                                        \
  auto stA = [&](int dbuf, int kb, int R) {                                    \
    gld_lds16(AP + (size_t)(R + srow8) * 1536 + kb + scb8,                     \
              (char*)smem + dbuf * 16384 + R * 128);                           \
  };                                                                           \
  auto stB = [&](int dbuf, int kb, int R) {                                    \
    gld_lds16(BP + (size_t)(R + srow8) * 1536 + kb + scb8,                     \
              (char*)smem + 32768 + dbuf * 12288 + R * 128);                   \
  };                                                                           \
  _Pragma("unroll")                                                            \
  for (int pt = 0; pt < 2; ++pt) {                                             \
    const int kb = pt * 128;                                                   \
    stA(pt, kb, wave * 8);      stA(pt, kb, 32 + wave * 8);                    \
    stA(pt, kb, 64 + wave * 8); stA(pt, kb, 96 + wave * 8);                    \
    stB(pt, kb, ReB0);          stB(pt, kb, ReB1);                             \
    stB(pt, kb, RlB);                                                          \
  }                                                                            \
  asm volatile("s_waitcnt vmcnt(7)" ::: "memory");                             \
  __builtin_amdgcn_s_barrier();                                                \
  for (int kt = 0; kt < 12; ++kt) {                                            \
    const int db = kt & 1;                                                     \
    const char* Ad = (const char*)smem + db * 16384;                           \
    const char* Bd = (const char*)smem + 32768 + db * 12288;                   \
    bf16x8 a[4][2], b[3][2];                                                   \
    /* ---- phase 1 ---- */                                                    \
    _Pragma("unroll")                                                          \
    for (int i = 0; i < 4; ++i)                                                \
      _Pragma("unroll")                                                        \
      for (int c = 0; c < 2; ++c)                                              \
        a[i][c] = *(const bf16x8*)(Ad + (wm * 64 + i * 16 + fr) * 128 +        \
                                   ((c * 64 + fq * 16) ^ swz));                \
    _Pragma("unroll")                                                          \
    for (int j = 0; j < 2; ++j)                                                \
      _Pragma("unroll")                                                        \
      for (int c = 0; c < 2; ++c)                                              \
        b[j][c] = *(const bf16x8*)(Bd + (wn * 48 + j * 16 + fr) * 128 +        \
                                   ((c * 64 + fq * 16) ^ swz));                \
    if (kt >= 1 && kt <= 10) stB(db ^ 1, (kt + 1) * 128, RlB);                 \
    if (kt < 11) asm volatile("s_waitcnt vmcnt(7)" ::: "memory");              \
    else         asm volatile("s_waitcnt vmcnt(0)" ::: "memory");              \
    __builtin_amdgcn_s_barrier();                                              \
    __builtin_amdgcn_s_setprio(1);                                             \
    _Pragma("unroll")                                                          \
    for (int i = 0; i < 4; ++i)                                                \
      _Pragma("unroll")                                                        \
      for (int j = 0; j < 2; ++j)                                              \
        _Pragma("unroll")                                                      \
        for (int c = 0; c < 2; ++c)                                            \
          acc[i][j] = __builtin_amdgcn_mfma_f32_16x16x32_bf16(                 \
              a[i][c], b[j][c], acc[i][j], 0, 0, 0);                           \
    __builtin_amdgcn_s_setprio(0);                                             \
    __builtin_amdgcn_s_barrier();                                              \
    /* ---- phase 2 ---- */                                                    \
    _Pragma("unroll")                                                          \
    for (int c = 0; c < 2; ++c)                                                \
      b[2][c] = *(const bf16x8*)(Bd + (wn * 48 + 32 + fr) * 128 +              \
                                 ((c * 64 + fq * 16) ^ swz));                  \
    if (kt <= 9) {                                                             \
      const int kb2 = (kt + 2) * 128;                                          \
      stA(db, kb2, wave * 8);      stA(db, kb2, 32 + wave * 8);                \
      stA(db, kb2, 64 + wave * 8); stA(db, kb2, 96 + wave * 8);                \
      stB(db, kb2, ReB0);          stB(db, kb2, ReB1);                         \
    }                                                                          \
    if (kt <= 9)       asm volatile("s_waitcnt vmcnt(6)" ::: "memory");        \
    else if (kt == 10) asm volatile("s_waitcnt vmcnt(1)" ::: "memory");        \
    else               asm volatile("s_waitcnt vmcnt(0)" ::: "memory");        \
    __builtin_amdgcn_s_barrier();                                              \
    __builtin_amdgcn_s_setprio(1);                                             \
    _Pragma("unroll")                                                          \
    for (int i = 0; i < 4; ++i)                                                \
      _Pragma("unroll")                                                        \
      for (int c = 0; c < 2; ++c)                                              \
        acc[i][2] = __builtin_amdgcn_mfma_f32_16x16x32_bf16(                   \
            a[i][c], b[2][c], acc[i][2], 0, 0, 0);                             \
    __builtin_amdgcn_s_setprio(0);                                             \
    __builtin_amdgcn_s_barrier();                                              \
  }

// ---------------------------------------------------------------------------
// GEMM1: qkv = Xb @ WT^T + b. 1536 wgs (64m x 24n of 96) = exactly 3 rounds
// at 2 blocks/CU -- zero tail. Epilogue: Q (pre-scaled)/K direct; V via
// per-wave [48][72] LDS transpose with per-dslot head/d (48-col waves
// straddle head boundaries).
// ---------------------------------------------------------------------------
__global__ __launch_bounds__(256, 2) void gemm_qkv(
    const unsigned short* __restrict__ Xb, const unsigned short* __restrict__ WT,
    const float* __restrict__ bias,
    unsigned short* __restrict__ Qo, unsigned short* __restrict__ Ko,
    unsigned short* __restrict__ VTo) {
  __shared__ __align__(16) unsigned short smem[28672];  // 56KB
  int flat = blockIdx.x;                             // 1536 wgs, %8==0
  flat = (flat & 7) * 192 + (flat >> 3);             // XCD-chunked swizzle
  const int m0 = (flat / 24) * 128;
  const int n0 = (flat % 24) * 96;
  const char* Ap = (const char*)(Xb + (size_t)m0 * MODELD);
  const char* Bp = (const char*)(WT + (size_t)n0 * MODELD);

  GEMM_CORE96(Ap, Bp)

  __builtin_amdgcn_s_barrier();       // LDS reuse guard for V scratch
  const int s = n0 / MODELD;          // 0=q 1=k 2=v (768/96=8 -> uniform)
  if (s < 2) {
    const float qs = (s == 0) ? QSC : 1.0f;
#pragma unroll
    for (int i = 0; i < 4; ++i) {
#pragma unroll
      for (int j = 0; j < 3; ++j) {
        const int col = n0 + wn * 48 + j * 16 + fr;
        const int rem = col - s * MODELD;
        const int h = rem >> 6, d = rem & 63;
        const float bv = bias[col];
#pragma unroll
        for (int r = 0; r < 4; ++r) {
          const int row = m0 + wm * 64 + i * 16 + fq * 4 + r;
          const int bb = row >> 10, n = row & 1023;
          const int bh = bb * NHEADS + h;
          const unsigned short val = f2bf((acc[i][j][r] + bv) * qs);
          if (s == 0) Qo[((size_t)bh * SEQ + n) * HDIM + d] = val;
          else        Ko[((size_t)bh * SEQ + n) * HDIM + d] = val;
        }
      }
    }
  } else {
    // ---- V epilogue: per-wave [48][72] transpose, per-dslot head ----
    unsigned short* T = smem + wave * 3456;          // 6912B per wave
#pragma unroll
    for (int i = 0; i < 4; ++i) {
#pragma unroll
      for (int j = 0; j < 3; ++j) {
        const int col = n0 + wn * 48 + j * 16 + fr;
        const float bv = bias[col];
        const int dl = j * 16 + fr;                  // 0..47 within wave span
        union { unsigned int u[2]; u16x4 v; } pk;
        pk.u[0] = pk2(acc[i][j][0] + bv, acc[i][j][1] + bv);
        pk.u[1] = pk2(acc[i][j][2] + bv, acc[i][j][3] + bv);
        *(u16x4*)&T[dl * 72 + i * 16 + fq * 4] = pk.v;
      }
    }
    asm volatile("s_waitcnt lgkmcnt(0)" ::: "memory");
    const int rowb = m0 + wm * 64;                   // 64 q-rows, one batch
    const int bb = rowb >> 10, nq = rowb & 1023;
#pragma unroll
    for (int u = 0; u < 6; ++u) {
      const int dslot = u * 8 + (lane >> 3);         // 0..47
      const int qc = (lane & 7) * 8;
      const int rem = n0 + wn * 48 + dslot - 2 * MODELD;
      const int h = rem >> 6, d = rem & 63;
      const int bh = bb * NHEADS + h;
      u16x8 v = *(const u16x8*)&T[dslot * 72 + qc];
      *(u16x8*)(VTo + ((size_t)bh * HDIM + d) * SEQ + nq + qc) = v;
    }
  }
}

// ---------------------------------------------------------------------------
// GEMM2: out = AO @ WT^T + b, fp32 out. 512 wgs (64m x 8n of 96) = exactly
// 1 round at 2 blocks/CU.
// ---------------------------------------------------------------------------
__global__ __launch_bounds__(256, 2) void gemm_proj(
    const unsigned short* __restrict__ A, const unsigned short* __restrict__ WT,
    const float* __restrict__ bias, float* __restrict__ Out) {
  __shared__ __align__(16) unsigned short smem[28672];  // 56KB
  int flat = blockIdx.x;                             // 512 wgs, %8==0
  flat = (flat & 7) * 64 + (flat >> 3);
  const int m0 = (flat / 8) * 128;
  const int n0 = (flat % 8) * 96;
  const char* Ap = (const char*)(A  + (size_t)m0 * MODELD);
  const char* Bp = (const char*)(WT + (size_t)n0 * MODELD);

  GEMM_CORE96(Ap, Bp)

#pragma unroll
  for (int i = 0; i < 4; ++i) {
#pragma unroll
    for (int j = 0; j < 3; ++j) {
      const int col = n0 + wn * 48 + j * 16 + fr;
      const float bv = bias[col];
#pragma unroll
      for (int r = 0; r < 4; ++r) {
        const int row = m0 + wm * 64 + i * 16 + fq * 4 + r;
        Out[(size_t)row * MODELD + col] = acc[i][j][r] + bv;
      }
    }
  }
}

// ---------------------------------------------------------------------------
// Flash attention v6 (unchanged): swapped QK^T, in-register P, no max
// tracking, ones-MFMA row-sum, tri-buffered K/V, counted vmcnt.
// ---------------------------------------------------------------------------
__global__ __launch_bounds__(256, 3) void attn_fused(
    const unsigned short* __restrict__ Q, const unsigned short* __restrict__ K,
    const unsigned short* __restrict__ VT, unsigned short* __restrict__ AO) {
  __shared__ __align__(16) unsigned short smem[24576];  // 48KB

  const int tid  = threadIdx.x;
  const int lane = tid & 63;
  const int wave = tid >> 6;

  const int flat = blockIdx.y * 8 + blockIdx.x;
  const int xcd = flat & 7, j = flat >> 3;
  const int bh = xcd * 12 + (j >> 3);
  const int qb = j & 7;
  const int b = bh / NHEADS, h = bh % NHEADS;
  const int q0 = qb * 128 + wave * 32;

  const unsigned short* Qp = Q  + (size_t)bh * SEQ * HDIM;
  const unsigned short* Kp = K  + (size_t)bh * SEQ * HDIM;
  const unsigned short* Vp = VT + (size_t)bh * HDIM * SEQ;

  const int fr = lane & 15;
  const int fq = lane >> 4;
  const int swz = (fr & 7) << 4;

  bf16x8 qf[2][2];
#pragma unroll
  for (int g = 0; g < 2; ++g)
#pragma unroll
    for (int c = 0; c < 2; ++c)
      qf[g][c] = *(const bf16x8*)(Qp + (size_t)(q0 + g * 16 + fr) * HDIM + c * 32 + fq * 8);

  const int srow_lo = (lane >> 3);
  const int scx = (((lane & 7) ^ srow_lo) << 4);

  f32x4 acc[2][4] = {};
  f32x4 accl[2] = {};
  bf16x8 ones;
#pragma unroll
  for (int i = 0; i < 8; ++i) ones[i] = (short)0x3F80;

  auto stage = [&](int buf, int kv0) {
    const char* Kb = (const char*)Kp + (size_t)kv0 * 128;
    const char* Vb = (const char*)Vp + (size_t)kv0 * 2;
#pragma unroll
    for (int u = 0; u < 2; ++u) {
      const int i = wave * 2 + u;
      const int r0 = i * 8 + srow_lo;
      gld_lds16(Kb + (size_t)r0 * 128  + scx, (char*)smem + buf * 8192 + i * 1024);
      gld_lds16(Vb + (size_t)r0 * 2048 + scx, (char*)smem + 24576 + buf * 8192 + i * 1024);
    }
  };

  stage(0, 0);
  stage(1, 64);

  int cur = 0;
  for (int t = 0; t < SEQ / 64; ++t) {
    if (t < SEQ / 64 - 1) asm volatile("s_waitcnt vmcnt(4)" ::: "memory");
    else                  asm volatile("s_waitcnt vmcnt(0)" ::: "memory");
    __builtin_amdgcn_s_barrier();
    if (t < SEQ / 64 - 2) {
      int sb = cur + 2; if (sb >= 3) sb -= 3;
      stage(sb, (t + 2) * 64);
    }

    const char* Kt = (const char*)smem + cur * 8192;
    const char* Vt = (const char*)smem + 24576 + cur * 8192;

    bf16x8 kf[4][2];
#pragma unroll
    for (int ng = 0; ng < 4; ++ng)
#pragma unroll
      for (int c = 0; c < 2; ++c)
        kf[ng][c] = *(const bf16x8*)(Kt + (ng * 16 + fr) * 128 + ((c * 64 + fq * 16) ^ swz));

    f32x4 S[2][4] = {};
    __builtin_amdgcn_s_setprio(1);
#pragma unroll
    for (int g = 0; g < 2; ++g)
#pragma unroll
      for (int ng = 0; ng < 4; ++ng)
#pragma unroll
        for (int c = 0; c < 2; ++c)
          S[g][ng] = __builtin_amdgcn_mfma_f32_16x16x32_bf16(kf[ng][c], qf[g][c], S[g][ng], 0, 0, 0);
    __builtin_amdgcn_s_setprio(0);

    bf16x8 pf[2][2];
#pragma unroll
    for (int g = 0; g < 2; ++g) {
      unsigned int u[4][2];
#pragma unroll
      for (int ng = 0; ng < 4; ++ng) {
        const float p0 = __builtin_amdgcn_exp2f(S[g][ng][0]);
        const float p1 = __builtin_amdgcn_exp2f(S[g][ng][1]);
        const float p2 = __builtin_amdgcn_exp2f(S[g][ng][2]);
        const float p3 = __builtin_amdgcn_exp2f(S[g][ng][3]);
        u[ng][0] = pk2(p0, p1);
        u[ng][1] = pk2(p2, p3);
      }
#pragma unroll
      for (int c = 0; c < 2; ++c) {
        union { unsigned int w[4]; bf16x8 v; } pp;
#pragma unroll
        for (int d2 = 0; d2 < 2; ++d2) {
          unsigned int e = u[2 * c][d2], o = u[2 * c + 1][d2];
          asm("v_permlane32_swap_b32 %0, %1" : "+v"(e), "+v"(o));
          asm("v_permlane16_swap_b32 %0, %1" : "+v"(e), "+v"(o));
          pp.w[d2] = e;
          pp.w[2 + d2] = o;
        }
        pf[g][c] = pp.v;
      }
    }

    bf16x8 vf[4][2];
#pragma unroll
    for (int df = 0; df < 4; ++df)
#pragma unroll
      for (int c = 0; c < 2; ++c)
        vf[df][c] = *(const bf16x8*)(Vt + (df * 16 + fr) * 128 + ((c * 64 + fq * 16) ^ swz));

    __builtin_amdgcn_s_setprio(1);
#pragma unroll
    for (int g = 0; g < 2; ++g) {
#pragma unroll
      for (int df = 0; df < 4; ++df)
#pragma unroll
        for (int c = 0; c < 2; ++c)
          acc[g][df] = __builtin_amdgcn_mfma_f32_16x16x32_bf16(pf[g][c], vf[df][c], acc[g][df], 0, 0, 0);
#pragma unroll
      for (int c = 0; c < 2; ++c)
        accl[g] = __builtin_amdgcn_mfma_f32_16x16x32_bf16(pf[g][c], ones, accl[g], 0, 0, 0);
    }
    __builtin_amdgcn_s_setprio(0);

    cur = (cur == 2) ? 0 : cur + 1;
  }

#pragma unroll
  for (int g = 0; g < 2; ++g) {
#pragma unroll
    for (int r = 0; r < 4; ++r) {
      const float inv = 1.0f / accl[g][r];
      const int q = q0 + g * 16 + fq * 4 + r;
      unsigned short* outp = AO + ((size_t)b * SEQ + q) * MODELD + h * HDIM;
#pragma unroll
      for (int df = 0; df < 4; ++df)
        outp[df * 16 + fr] = f2bf(acc[g][df][r] * inv);
    }
  }
}

// ---------------------------------------------------------------------------
extern "C" void kernel_launch(void* const* d_in, const int* in_sizes, int n_in,
                              void* d_out, int out_size, void* d_ws, size_t ws_size,
                              hipStream_t stream) {
  const float* x      = (const float*)d_in[0];
  const float* w_qkv  = (const float*)d_in[1];
  const float* b_qkv  = (const float*)d_in[2];
  const float* w_proj = (const float*)d_in[3];
  const float* b_proj = (const float*)d_in[4];
  float* out = (float*)d_out;

  unsigned short* ws = (unsigned short*)d_ws;
  unsigned short* wqkvT  = ws;                               // [2304][768]
  unsigned short* wprojT = wqkvT + (size_t)QKVD * MODELD;    // [768][768]
  unsigned short* Qw     = wprojT + (size_t)MODELD * MODELD; // [96][1024][64]
  unsigned short* Kw     = Qw + (size_t)BHEADS * SEQ * HDIM;
  unsigned short* VTw    = Kw + (size_t)BHEADS * SEQ * HDIM; // [96][64][1024]
  unsigned short* AO     = VTw + (size_t)BHEADS * SEQ * HDIM;// [8192][768]
  unsigned short* Xb     = AO + (size_t)NBATCH * SEQ * MODELD;// [8192][768]

  prep<<<dim3(5376), 256, 0, stream>>>(x, Xb, w_qkv, wqkvT, w_proj, wprojT);
  gemm_qkv<<<dim3((QKVD / 96) * ((NBATCH * SEQ) / 128)), 256, 0, stream>>>(
      Xb, wqkvT, b_qkv, Qw, Kw, VTw);
  attn_fused<<<dim3(SEQ / 128, BHEADS), 256, 0, stream>>>(Qw, Kw, VTw, AO);
  gemm_proj<<<dim3((MODELD / 96) * ((NBATCH * SEQ) / 128)), 256, 0, stream>>>(
      AO, wprojT, b_proj, out);
}